// Round 11
// baseline (475.110 us; speedup 1.0000x reference)
//
#include <hip/hip_runtime.h>
#include <hip/hip_bf16.h>

#define B_ 2
#define S_ 2048
#define D_ 1024
#define H_ 16
#define HD_ 64

typedef __attribute__((ext_vector_type(8))) short short8;
typedef __attribute__((ext_vector_type(4))) float f32x4;
typedef __attribute__((ext_vector_type(16))) float f32x16;
typedef __attribute__((ext_vector_type(4))) unsigned short us4;

static __device__ __forceinline__ ushort f2bf(float x) {
  __hip_bfloat16 h = __float2bfloat16(x);
  return *reinterpret_cast<ushort*>(&h);
}

static __device__ __forceinline__ void gld_lds16(void* lds, const void* g) {
  __builtin_amdgcn_global_load_lds(
      (__attribute__((address_space(1))) void*)(g),
      (__attribute__((address_space(3))) void*)(lds), 16, 0, 0);
}

// ---------------- fused prep: x->bf16 + Wqkv^T + Wo^T in ONE launch ----------------

static __device__ __forceinline__ void transpose_tile(const float* __restrict__ in,
                                                      ushort* __restrict__ out,
                                                      int K, int N, int bn, int bk,
                                                      int tx, int ty) {
  __shared__ float tile[32][33];
  #pragma unroll
  for (int i = ty; i < 32; i += 8)
    tile[i][tx] = in[(size_t)(bk + i) * N + bn + tx];
  __syncthreads();
  #pragma unroll
  for (int i = ty; i < 32; i += 8)
    out[(size_t)(bn + i) * K + bk + tx] = f2bf(tile[tx][i]);
}

// grid: [0,4096) cvt x | [4096,7168) Wqkv^T (96x32 tiles) | [7168,8192) Wo^T (32x32)
__global__ __launch_bounds__(256) void prep_all(const float4* __restrict__ x4,
                                                ushort* __restrict__ xbf,
                                                const float* __restrict__ Wqkv,
                                                ushort* __restrict__ wqkvT,
                                                const float* __restrict__ Wo,
                                                ushort* __restrict__ woT) {
  const int blk = blockIdx.x, tid = threadIdx.x;
  if (blk < 4096) {
    const int i = blk * 256 + tid;
    float4 v = x4[i];
    ushort4 o;
    o.x = f2bf(v.x); o.y = f2bf(v.y); o.z = f2bf(v.z); o.w = f2bf(v.w);
    *reinterpret_cast<ushort4*>(xbf + (size_t)i * 4) = o;
  } else if (blk < 7168) {
    const int sub = blk - 4096;
    transpose_tile(Wqkv, wqkvT, D_, 3 * D_, (sub % 96) * 32, (sub / 96) * 32,
                   tid & 31, tid >> 5);
  } else {
    const int sub = blk - 7168;
    transpose_tile(Wo, woT, D_, D_, (sub % 32) * 32, (sub / 32) * 32,
                   tid & 31, tid >> 5);
  }
}

// ---------------- GEMM: C = A @ Bt^T + bias (T1 XCD-chunked tile swizzle) ----------------
template <bool OUT_BF16>
__global__ __launch_bounds__(256) void gemm_bt(const ushort* __restrict__ A,
                                               const ushort* __restrict__ Bt,
                                               const float* __restrict__ bias,
                                               ushort* __restrict__ Cb,
                                               float* __restrict__ Cf,
                                               int M, int N, int K) {
  __shared__ __align__(16) ushort As[128 * 32];
  __shared__ __align__(16) ushort Bs[128 * 32];
  const int tid = threadIdx.x;
  const int lane = tid & 63, wid = tid >> 6;
  const int wr = wid >> 1, wc = wid & 1;

  const int nwg = gridDim.x * gridDim.y;
  const int lin = blockIdx.x + gridDim.x * blockIdx.y;
  const int nl = (lin & 7) * (nwg >> 3) + (lin >> 3);
  const int row0 = (nl % gridDim.x) * 128, col0 = (nl / gridDim.x) * 128;

  const int l15 = lane & 15, lhi = lane >> 4;

  f32x4 acc[4][4];
  #pragma unroll
  for (int i = 0; i < 4; ++i)
    #pragma unroll
    for (int j = 0; j < 4; ++j)
      acc[i][j] = f32x4{0.f, 0.f, 0.f, 0.f};

  const int sr = tid >> 2;
  const int scol = (tid & 3) * 8;

  for (int k0 = 0; k0 < K; k0 += 32) {
    gld_lds16(&As[(size_t)tid * 8],        &A[(size_t)(row0 + sr) * K + k0 + scol]);
    gld_lds16(&As[2048 + (size_t)tid * 8], &A[(size_t)(row0 + 64 + sr) * K + k0 + scol]);
    gld_lds16(&Bs[(size_t)tid * 8],        &Bt[(size_t)(col0 + sr) * K + k0 + scol]);
    gld_lds16(&Bs[2048 + (size_t)tid * 8], &Bt[(size_t)(col0 + 64 + sr) * K + k0 + scol]);
    __syncthreads();

    short8 af[4], bfr[4];
    #pragma unroll
    for (int mt = 0; mt < 4; ++mt)
      af[mt] = *(const short8*)&As[(wr * 64 + mt * 16 + l15) * 32 + lhi * 8];
    #pragma unroll
    for (int nt = 0; nt < 4; ++nt)
      bfr[nt] = *(const short8*)&Bs[(wc * 64 + nt * 16 + l15) * 32 + lhi * 8];
    #pragma unroll
    for (int mt = 0; mt < 4; ++mt)
      #pragma unroll
      for (int nt = 0; nt < 4; ++nt)
        acc[mt][nt] = __builtin_amdgcn_mfma_f32_16x16x32_bf16(af[mt], bfr[nt], acc[mt][nt], 0, 0, 0);
    __syncthreads();
  }

  const int orow = row0 + wr * 64;
  const int ocol = col0 + wc * 64 + l15;
  #pragma unroll
  for (int mt = 0; mt < 4; ++mt) {
    #pragma unroll
    for (int nt = 0; nt < 4; ++nt) {
      const int gc = ocol + nt * 16;
      const float bv = bias[gc];
      #pragma unroll
      for (int r = 0; r < 4; ++r) {
        const int gr = orow + mt * 16 + lhi * 4 + r;
        const float v = acc[mt][nt][r] + bv;
        if (OUT_BF16) Cb[(size_t)gr * N + gc] = f2bf(v);
        else          Cf[(size_t)gr * N + gc] = v;
      }
    }
  }
}

// ---------------- flash attention: r9 body + INTRA-BLOCK split-K ----------------
// 8 waves / 512 threads: waves 0-3 (grp 0) process keys [0,1024), waves 4-7 (grp 1)
// keys [1024,2048) for the SAME 128 q-rows.  4096 waves total = 4 waves/SIMD (2x TLP)
// with HBM traffic identical to the single-group version (disjoint tiles/mask within
// one block / one L2).  End: grp1 parks (o,m,l) in LDS, grp0 does the exact merge.
__global__ __launch_bounds__(512, 4) void flash_attn(const ushort* __restrict__ qkv,
                                                     const float* __restrict__ mask,
                                                     ushort* __restrict__ values) {
  __shared__ __align__(16) ushort Ks[2][2][64 * 64];
  __shared__ __align__(16) ushort Vt[2][2][64 * 64];

  const int tid = threadIdx.x;
  const int lane = tid & 63, wid = tid >> 6;
  const int grp = wid >> 2, wi = wid & 2 ? (wid & 3) : (wid & 3); // wi = wid&3
  const int l31 = lane & 31, lhalf = lane >> 5;
  const int qt = blockIdx.x, bh = blockIdx.y, b = bh >> 4, h = bh & 15;
  const size_t base = (size_t)b * S_ * 3072 + (size_t)h * 192;
  const size_t gkoff = (size_t)grp * 1024 * 3072;
  const int q = qt * 128 + (wid & 3) * 32 + l31;
  const int NT = 16;                       // 16 x 64 keys per group

  short8 qf[4];
  {
    const ushort* qrow = qkv + base + (size_t)q * 3072 + lhalf * 8;
    qf[0] = *(const short8*)(qrow);
    qf[1] = *(const short8*)(qrow + 16);
    qf[2] = *(const short8*)(qrow + 32);
    qf[3] = *(const short8*)(qrow + 48);
  }

  const int ltid = tid & 255;              // staging id within group
  const int srow = ltid >> 3, sch = ltid & 7;
  const int hsr = (srow ^ (srow >> 3)) & 7;
  const int scs = sch ^ hsr;
  const int kg = ltid & 15, d0 = (ltid >> 4) * 4;
  const int skg = (kg & 12) | ((kg & 1) << 1) | ((kg >> 1) & 1);

  float m_run = -3.0e38f, l_run = 0.f;
  f32x16 o[2];
  #pragma unroll
  for (int dg = 0; dg < 2; ++dg)
    #pragma unroll
    for (int i = 0; i < 16; ++i) o[dg][i] = 0.f;

  const float* mrow = mask + ((size_t)b * S_ + q) * S_ + grp * 1024;
  us4 vr[4];
  f32x16 scA[2], scB[2];

#define QKT_(SCDST, KSBUF)                                                     \
  {                                                                            \
    _Pragma("unroll")                                                          \
    for (int g = 0; g < 2; ++g) {                                              \
      const int row_ = g * 32 + l31;                                           \
      const int hk_ = (row_ ^ (row_ >> 3)) & 7;                                \
      const ushort* kp_ = &(KSBUF)[row_ * 64];                                 \
      f32x16 s_;                                                               \
      _Pragma("unroll")                                                        \
      for (int i = 0; i < 16; ++i) s_[i] = 0.f;                                \
      _Pragma("unroll")                                                        \
      for (int kd = 0; kd < 4; ++kd) {                                         \
        short8 kf_ = *(const short8*)&kp_[(((kd * 2 + lhalf) ^ hk_) & 7) * 8]; \
        s_ = __builtin_amdgcn_mfma_f32_32x32x16_bf16(kf_, qf[kd], s_, 0, 0, 0);\
      }                                                                        \
      (SCDST)[g] = s_;                                                         \
    }                                                                          \
  }

#define VSCATTER_(VTBUF)                                                       \
  {                                                                            \
    _Pragma("unroll")                                                          \
    for (int dd = 0; dd < 4; ++dd) {                                           \
      const int d_ = d0 + dd;                                                  \
      const int hd_ = (d_ ^ (d_ >> 3)) & 7;                                    \
      us4 w_;                                                                  \
      w_[0] = vr[0][dd]; w_[1] = vr[1][dd];                                    \
      w_[2] = vr[2][dd]; w_[3] = vr[3][dd];                                    \
      *(us4*)&(VTBUF)[d_ * 64 + (((skg >> 1) ^ hd_) & 7) * 8 + (skg & 1) * 4] = w_; \
    }                                                                          \
  }

#define HALF_(T, SCCUR, SCNEXT)                                                \
  {                                                                            \
    const int t_ = (T);                                                        \
    const bool pre1_ = (t_ + 1 < NT), pre2_ = (t_ + 2 < NT);                   \
    if (pre2_) {                                                               \
      const ushort* kn_ = qkv + base + gkoff + (size_t)(t_ + 2) * 64 * 3072 +  \
                          (size_t)srow * 3072 + 64;                            \
      gld_lds16(&Ks[grp][t_ & 1][ltid * 8],        kn_ + scs * 8);             \
      gld_lds16(&Ks[grp][t_ & 1][2048 + ltid * 8], kn_ + (size_t)32 * 3072 + (scs ^ 4) * 8); \
    }                                                                          \
    if (pre1_) {                                                               \
      const ushort* vn_ = qkv + base + gkoff + (size_t)(t_ + 1) * 64 * 3072 + 128 + d0; \
      _Pragma("unroll")                                                        \
      for (int kk = 0; kk < 4; ++kk)                                           \
        vr[kk] = *(const us4*)(vn_ + (size_t)(kg * 4 + kk) * 3072);            \
    }                                                                          \
    f32x4 mk_[8];                                                              \
    {                                                                          \
      const float* mp_ = mrow + t_ * 64 + lhalf * 4;                           \
      _Pragma("unroll")                                                        \
      for (int i = 0; i < 8; ++i)                                              \
        mk_[i] = *(const f32x4*)(mp_ + (i >> 2) * 32 + (i & 3) * 8);           \
    }                                                                          \
    __builtin_amdgcn_s_setprio(1);                                             \
    if (pre1_) QKT_(SCNEXT, Ks[grp][(t_ + 1) & 1]);                            \
    _Pragma("unroll")                                                          \
    for (int g = 0; g < 2; ++g)                                                \
      _Pragma("unroll")                                                        \
      for (int r = 0; r < 16; ++r)                                             \
        (SCCUR)[g][r] = (SCCUR)[g][r] * 0.125f + mk_[g * 4 + (r >> 2)][r & 3]; \
    float mx_ = (SCCUR)[0][0];                                                 \
    _Pragma("unroll")                                                          \
    for (int g = 0; g < 2; ++g)                                                \
      _Pragma("unroll")                                                        \
      for (int r = 0; r < 16; ++r) mx_ = fmaxf(mx_, (SCCUR)[g][r]);            \
    mx_ = fmaxf(mx_, __shfl_xor(mx_, 32));                                     \
    if (__any(mx_ > m_run + 8.0f)) {                                           \
      const float mnew_ = fmaxf(m_run, mx_);                                   \
      const float alpha_ = __expf(m_run - mnew_);                              \
      m_run = mnew_;                                                           \
      l_run *= alpha_;                                                         \
      _Pragma("unroll")                                                        \
      for (int dg = 0; dg < 2; ++dg)                                           \
        _Pragma("unroll")                                                      \
        for (int i = 0; i < 16; ++i) o[dg][i] *= alpha_;                       \
    }                                                                          \
    float ps_ = 0.f;                                                           \
    _Pragma("unroll")                                                          \
    for (int g = 0; g < 2; ++g)                                                \
      _Pragma("unroll")                                                        \
      for (int r = 0; r < 16; ++r) {                                           \
        const float p_ = __expf((SCCUR)[g][r] - m_run);                        \
        (SCCUR)[g][r] = p_;                                                    \
        ps_ += p_;                                                             \
      }                                                                        \
    ps_ += __shfl_xor(ps_, 32);                                                \
    l_run += ps_;                                                              \
    short8 pf_[4];                                                             \
    _Pragma("unroll")                                                          \
    for (int ks = 0; ks < 4; ++ks)                                             \
      _Pragma("unroll")                                                        \
      for (int j = 0; j < 8; ++j)                                              \
        pf_[ks][j] = (short)f2bf((SCCUR)[ks >> 1][8 * (ks & 1) + j]);          \
    _Pragma("unroll")                                                          \
    for (int dg = 0; dg < 2; ++dg) {                                           \
      const int d_ = dg * 32 + l31;                                            \
      const int hv_ = (d_ ^ (d_ >> 3)) & 7;                                    \
      const ushort* vp_ = &Vt[grp][t_ & 1][d_ * 64];                           \
      _Pragma("unroll")                                                        \
      for (int ks = 0; ks < 4; ++ks) {                                         \
        short8 vf_ = *(const short8*)&vp_[(((ks * 2 + lhalf) ^ hv_) & 7) * 8]; \
        o[dg] = __builtin_amdgcn_mfma_f32_32x32x16_bf16(vf_, pf_[ks], o[dg], 0, 0, 0); \
      }                                                                        \
    }                                                                          \
    __builtin_amdgcn_s_setprio(0);                                             \
    if (pre1_) VSCATTER_(Vt[grp][(t_ + 1) & 1]);                               \
    __syncthreads();                                                           \
  }

  // ---- prologue: each group stages its tiles 0,1 -> LDS, V(0); QK(0) -> scA ----
  {
    const ushort* k0 = qkv + base + gkoff + (size_t)srow * 3072 + 64;
    gld_lds16(&Ks[grp][0][ltid * 8],        k0 + scs * 8);
    gld_lds16(&Ks[grp][0][2048 + ltid * 8], k0 + (size_t)32 * 3072 + (scs ^ 4) * 8);
    const ushort* k1 = k0 + (size_t)64 * 3072;
    gld_lds16(&Ks[grp][1][ltid * 8],        k1 + scs * 8);
    gld_lds16(&Ks[grp][1][2048 + ltid * 8], k1 + (size_t)32 * 3072 + (scs ^ 4) * 8);
    #pragma unroll
    for (int kk = 0; kk < 4; ++kk)
      vr[kk] = *(const us4*)(qkv + base + gkoff + (size_t)(kg * 4 + kk) * 3072 + 128 + d0);
    VSCATTER_(Vt[grp][0]);
    __syncthreads();
    QKT_(scA, Ks[grp][0]);
  }

  for (int tp = 0; tp < NT; tp += 2) {
    HALF_(tp,     scA, scB);
    HALF_(tp + 1, scB, scA);
  }

  // ---- combine the two groups' partials (LDS handoff, XOR-swizzled rows) ----
  float* cb   = (float*)&Vt[0][0][0];      // 128 x 64 f32 = 32 KB
  float2* cml = (float2*)&Ks[0][0][0];     // 128 x 8 B = 1 KB
  const int qloc = (wid & 3) * 32 + l31;
  const int cswz = (qloc & 7) << 3;
  if (grp == 1) {
    #pragma unroll
    for (int dg = 0; dg < 2; ++dg)
      #pragma unroll
      for (int quad = 0; quad < 4; ++quad) {
        f32x4 w;
        #pragma unroll
        for (int r = 0; r < 4; ++r) w[r] = o[dg][quad * 4 + r];
        *(f32x4*)&cb[qloc * 64 + ((dg * 32 + quad * 8 + lhalf * 4) ^ cswz)] = w;
      }
    if (lhalf == 0) cml[qloc] = make_float2(m_run, l_run);
  }
  __syncthreads();
  if (grp == 0) {
    const float2 ml1 = cml[qloc];
    const float m = fmaxf(m_run, ml1.x);
    const float w0 = __expf(m_run - m), w1 = __expf(ml1.x - m);
    const float inv = 1.0f / (l_run * w0 + ml1.y * w1);
    ushort* vout = values + ((size_t)bh * S_ + q) * 64;
    #pragma unroll
    for (int dg = 0; dg < 2; ++dg)
      #pragma unroll
      for (int quad = 0; quad < 4; ++quad) {
        const f32x4 o1 = *(const f32x4*)&cb[qloc * 64 + ((dg * 32 + quad * 8 + lhalf * 4) ^ cswz)];
        us4 w;
        #pragma unroll
        for (int r = 0; r < 4; ++r)
          w[r] = f2bf((o[dg][quad * 4 + r] * w0 + o1[r] * w1) * inv);
        *(us4*)(vout + dg * 32 + quad * 8 + lhalf * 4) = w;
      }
  }
#undef HALF_
#undef VSCATTER_
#undef QKT_
}

// ---------------- launch ----------------

extern "C" void kernel_launch(void* const* d_in, const int* in_sizes, int n_in,
                              void* d_out, int out_size, void* d_ws, size_t ws_size,
                              hipStream_t stream) {
  const float* x    = (const float*)d_in[0];
  const float* mask = (const float*)d_in[1];
  const float* Wqkv = (const float*)d_in[2];
  const float* bqkv = (const float*)d_in[3];
  const float* Wo   = (const float*)d_in[4];
  const float* bo   = (const float*)d_in[5];
  float* out = (float*)d_out;

  char* ws = (char*)d_ws;
  ushort* xbf    = (ushort*)(ws + 0);
  ushort* vals   = (ushort*)(ws + 0);
  ushort* wqkvT  = (ushort*)(ws + 8388608);
  ushort* woT    = (ushort*)(ws + 14680064);
  ushort* qkv    = (ushort*)(ws + 16777216);

  prep_all<<<8192, 256, 0, stream>>>((const float4*)x, xbf, Wqkv, wqkvT, Wo, woT);
  gemm_bt<true><<<dim3((B_ * S_) / 128, (3 * D_) / 128), 256, 0, stream>>>(
      xbf, wqkvT, bqkv, qkv, nullptr, B_ * S_, 3 * D_, D_);
  flash_attn<<<dim3(S_ / 128, B_ * H_), 512, 0, stream>>>(qkv, mask, vals);
  gemm_bt<false><<<dim3((B_ * S_) / 128, D_ / 128), 256, 0, stream>>>(
      vals, woT, bo, nullptr, out, B_ * S_, D_, D_);
}

// Round 12
// 208.861 us; speedup vs baseline: 2.2748x; 2.2748x over previous
//
#include <hip/hip_runtime.h>
#include <hip/hip_bf16.h>

#define B_ 2
#define S_ 2048
#define D_ 1024
#define H_ 16
#define HD_ 64

typedef __attribute__((ext_vector_type(8))) short short8;
typedef __attribute__((ext_vector_type(4))) float f32x4;
typedef __attribute__((ext_vector_type(16))) float f32x16;
typedef __attribute__((ext_vector_type(4))) unsigned short us4;

static __device__ __forceinline__ ushort f2bf(float x) {
  __hip_bfloat16 h = __float2bfloat16(x);
  return *reinterpret_cast<ushort*>(&h);
}

static __device__ __forceinline__ void gld_lds16(void* lds, const void* g) {
  __builtin_amdgcn_global_load_lds(
      (__attribute__((address_space(1))) void*)(g),
      (__attribute__((address_space(3))) void*)(lds), 16, 0, 0);
}

// ---------------- fused prep: x->bf16 + Wqkv^T + Wo^T in ONE launch ----------------

static __device__ __forceinline__ void transpose_tile(const float* __restrict__ in,
                                                      ushort* __restrict__ out,
                                                      int K, int N, int bn, int bk,
                                                      int tx, int ty) {
  __shared__ float tile[32][33];
  #pragma unroll
  for (int i = ty; i < 32; i += 8)
    tile[i][tx] = in[(size_t)(bk + i) * N + bn + tx];
  __syncthreads();
  #pragma unroll
  for (int i = ty; i < 32; i += 8)
    out[(size_t)(bn + i) * K + bk + tx] = f2bf(tile[tx][i]);
}

// grid: [0,4096) cvt x | [4096,7168) Wqkv^T (96x32 tiles) | [7168,8192) Wo^T (32x32)
__global__ __launch_bounds__(256) void prep_all(const float4* __restrict__ x4,
                                                ushort* __restrict__ xbf,
                                                const float* __restrict__ Wqkv,
                                                ushort* __restrict__ wqkvT,
                                                const float* __restrict__ Wo,
                                                ushort* __restrict__ woT) {
  const int blk = blockIdx.x, tid = threadIdx.x;
  if (blk < 4096) {
    const int i = blk * 256 + tid;
    float4 v = x4[i];
    ushort4 o;
    o.x = f2bf(v.x); o.y = f2bf(v.y); o.z = f2bf(v.z); o.w = f2bf(v.w);
    *reinterpret_cast<ushort4*>(xbf + (size_t)i * 4) = o;
  } else if (blk < 7168) {
    const int sub = blk - 4096;
    transpose_tile(Wqkv, wqkvT, D_, 3 * D_, (sub % 96) * 32, (sub / 96) * 32,
                   tid & 31, tid >> 5);
  } else {
    const int sub = blk - 7168;
    transpose_tile(Wo, woT, D_, D_, (sub % 32) * 32, (sub / 32) * 32,
                   tid & 31, tid >> 5);
  }
}

// ---------------- GEMM: C = A @ Bt^T + bias (T1 XCD-chunked tile swizzle) ----------------
template <bool OUT_BF16>
__global__ __launch_bounds__(256) void gemm_bt(const ushort* __restrict__ A,
                                               const ushort* __restrict__ Bt,
                                               const float* __restrict__ bias,
                                               ushort* __restrict__ Cb,
                                               float* __restrict__ Cf,
                                               int M, int N, int K) {
  __shared__ __align__(16) ushort As[128 * 32];
  __shared__ __align__(16) ushort Bs[128 * 32];
  const int tid = threadIdx.x;
  const int lane = tid & 63, wid = tid >> 6;
  const int wr = wid >> 1, wc = wid & 1;

  const int nwg = gridDim.x * gridDim.y;
  const int lin = blockIdx.x + gridDim.x * blockIdx.y;
  const int nl = (lin & 7) * (nwg >> 3) + (lin >> 3);
  const int row0 = (nl % gridDim.x) * 128, col0 = (nl / gridDim.x) * 128;

  const int l15 = lane & 15, lhi = lane >> 4;

  f32x4 acc[4][4];
  #pragma unroll
  for (int i = 0; i < 4; ++i)
    #pragma unroll
    for (int j = 0; j < 4; ++j)
      acc[i][j] = f32x4{0.f, 0.f, 0.f, 0.f};

  const int sr = tid >> 2;
  const int scol = (tid & 3) * 8;

  for (int k0 = 0; k0 < K; k0 += 32) {
    gld_lds16(&As[(size_t)tid * 8],        &A[(size_t)(row0 + sr) * K + k0 + scol]);
    gld_lds16(&As[2048 + (size_t)tid * 8], &A[(size_t)(row0 + 64 + sr) * K + k0 + scol]);
    gld_lds16(&Bs[(size_t)tid * 8],        &Bt[(size_t)(col0 + sr) * K + k0 + scol]);
    gld_lds16(&Bs[2048 + (size_t)tid * 8], &Bt[(size_t)(col0 + 64 + sr) * K + k0 + scol]);
    __syncthreads();

    short8 af[4], bfr[4];
    #pragma unroll
    for (int mt = 0; mt < 4; ++mt)
      af[mt] = *(const short8*)&As[(wr * 64 + mt * 16 + l15) * 32 + lhi * 8];
    #pragma unroll
    for (int nt = 0; nt < 4; ++nt)
      bfr[nt] = *(const short8*)&Bs[(wc * 64 + nt * 16 + l15) * 32 + lhi * 8];
    #pragma unroll
    for (int mt = 0; mt < 4; ++mt)
      #pragma unroll
      for (int nt = 0; nt < 4; ++nt)
        acc[mt][nt] = __builtin_amdgcn_mfma_f32_16x16x32_bf16(af[mt], bfr[nt], acc[mt][nt], 0, 0, 0);
    __syncthreads();
  }

  const int orow = row0 + wr * 64;
  const int ocol = col0 + wc * 64 + l15;
  #pragma unroll
  for (int mt = 0; mt < 4; ++mt) {
    #pragma unroll
    for (int nt = 0; nt < 4; ++nt) {
      const int gc = ocol + nt * 16;
      const float bv = bias[gc];
      #pragma unroll
      for (int r = 0; r < 4; ++r) {
        const int gr = orow + mt * 16 + lhi * 4 + r;
        const float v = acc[mt][nt][r] + bv;
        if (OUT_BF16) Cb[(size_t)gr * N + gc] = f2bf(v);
        else          Cf[(size_t)gr * N + gc] = v;
      }
    }
  }
}

// ---------------- flash attention: r9 body + INTRA-BLOCK split-K ----------------
// 8 waves / 512 threads: waves 0-3 (grp 0) process keys [0,1024), waves 4-7 (grp 1)
// keys [1024,2048) for the SAME 128 q-rows.  4096 waves total -> 4 waves/SIMD.
// launch_bounds (512,2): allocator gets >=128 VGPR so the ~110-reg body does NOT
// spill (r11's (512,4) forced a 64-reg cap -> scratch catastrophe).
__global__ __launch_bounds__(512, 2) void flash_attn(const ushort* __restrict__ qkv,
                                                     const float* __restrict__ mask,
                                                     ushort* __restrict__ values) {
  __shared__ __align__(16) ushort Ks[2][2][64 * 64];
  __shared__ __align__(16) ushort Vt[2][2][64 * 64];

  const int tid = threadIdx.x;
  const int lane = tid & 63, wid = tid >> 6;
  const int grp = wid >> 2;
  const int l31 = lane & 31, lhalf = lane >> 5;
  const int qt = blockIdx.x, bh = blockIdx.y, b = bh >> 4, h = bh & 15;
  const size_t base = (size_t)b * S_ * 3072 + (size_t)h * 192;
  const size_t gkoff = (size_t)grp * 1024 * 3072;
  const int q = qt * 128 + (wid & 3) * 32 + l31;
  const int NT = 16;                       // 16 x 64 keys per group

  short8 qf[4];
  {
    const ushort* qrow = qkv + base + (size_t)q * 3072 + lhalf * 8;
    qf[0] = *(const short8*)(qrow);
    qf[1] = *(const short8*)(qrow + 16);
    qf[2] = *(const short8*)(qrow + 32);
    qf[3] = *(const short8*)(qrow + 48);
  }

  const int ltid = tid & 255;              // staging id within group
  const int srow = ltid >> 3, sch = ltid & 7;
  const int hsr = (srow ^ (srow >> 3)) & 7;
  const int scs = sch ^ hsr;
  const int kg = ltid & 15, d0 = (ltid >> 4) * 4;
  const int skg = (kg & 12) | ((kg & 1) << 1) | ((kg >> 1) & 1);

  float m_run = -3.0e38f, l_run = 0.f;
  f32x16 o[2];
  #pragma unroll
  for (int dg = 0; dg < 2; ++dg)
    #pragma unroll
    for (int i = 0; i < 16; ++i) o[dg][i] = 0.f;

  const float* mrow = mask + ((size_t)b * S_ + q) * S_ + grp * 1024;
  us4 vr[4];
  f32x16 scA[2], scB[2];

#define QKT_(SCDST, KSBUF)                                                     \
  {                                                                            \
    _Pragma("unroll")                                                          \
    for (int g = 0; g < 2; ++g) {                                              \
      const int row_ = g * 32 + l31;                                           \
      const int hk_ = (row_ ^ (row_ >> 3)) & 7;                                \
      const ushort* kp_ = &(KSBUF)[row_ * 64];                                 \
      f32x16 s_;                                                               \
      _Pragma("unroll")                                                        \
      for (int i = 0; i < 16; ++i) s_[i] = 0.f;                                \
      _Pragma("unroll")                                                        \
      for (int kd = 0; kd < 4; ++kd) {                                         \
        short8 kf_ = *(const short8*)&kp_[(((kd * 2 + lhalf) ^ hk_) & 7) * 8]; \
        s_ = __builtin_amdgcn_mfma_f32_32x32x16_bf16(kf_, qf[kd], s_, 0, 0, 0);\
      }                                                                        \
      (SCDST)[g] = s_;                                                         \
    }                                                                          \
  }

#define VSCATTER_(VTBUF)                                                       \
  {                                                                            \
    _Pragma("unroll")                                                          \
    for (int dd = 0; dd < 4; ++dd) {                                           \
      const int d_ = d0 + dd;                                                  \
      const int hd_ = (d_ ^ (d_ >> 3)) & 7;                                    \
      us4 w_;                                                                  \
      w_[0] = vr[0][dd]; w_[1] = vr[1][dd];                                    \
      w_[2] = vr[2][dd]; w_[3] = vr[3][dd];                                    \
      *(us4*)&(VTBUF)[d_ * 64 + (((skg >> 1) ^ hd_) & 7) * 8 + (skg & 1) * 4] = w_; \
    }                                                                          \
  }

#define HALF_(T, SCCUR, SCNEXT)                                                \
  {                                                                            \
    const int t_ = (T);                                                        \
    const bool pre1_ = (t_ + 1 < NT), pre2_ = (t_ + 2 < NT);                   \
    if (pre2_) {                                                               \
      const ushort* kn_ = qkv + base + gkoff + (size_t)(t_ + 2) * 64 * 3072 +  \
                          (size_t)srow * 3072 + 64;                            \
      gld_lds16(&Ks[grp][t_ & 1][ltid * 8],        kn_ + scs * 8);             \
      gld_lds16(&Ks[grp][t_ & 1][2048 + ltid * 8], kn_ + (size_t)32 * 3072 + (scs ^ 4) * 8); \
    }                                                                          \
    if (pre1_) {                                                               \
      const ushort* vn_ = qkv + base + gkoff + (size_t)(t_ + 1) * 64 * 3072 + 128 + d0; \
      _Pragma("unroll")                                                        \
      for (int kk = 0; kk < 4; ++kk)                                           \
        vr[kk] = *(const us4*)(vn_ + (size_t)(kg * 4 + kk) * 3072);            \
    }                                                                          \
    f32x4 mk_[8];                                                              \
    {                                                                          \
      const float* mp_ = mrow + t_ * 64 + lhalf * 4;                           \
      _Pragma("unroll")                                                        \
      for (int i = 0; i < 8; ++i)                                              \
        mk_[i] = *(const f32x4*)(mp_ + (i >> 2) * 32 + (i & 3) * 8);           \
    }                                                                          \
    __builtin_amdgcn_s_setprio(1);                                             \
    if (pre1_) QKT_(SCNEXT, Ks[grp][(t_ + 1) & 1]);                            \
    _Pragma("unroll")                                                          \
    for (int g = 0; g < 2; ++g)                                                \
      _Pragma("unroll")                                                        \
      for (int r = 0; r < 16; ++r)                                             \
        (SCCUR)[g][r] = (SCCUR)[g][r] * 0.125f + mk_[g * 4 + (r >> 2)][r & 3]; \
    float mx_ = (SCCUR)[0][0];                                                 \
    _Pragma("unroll")                                                          \
    for (int g = 0; g < 2; ++g)                                                \
      _Pragma("unroll")                                                        \
      for (int r = 0; r < 16; ++r) mx_ = fmaxf(mx_, (SCCUR)[g][r]);            \
    mx_ = fmaxf(mx_, __shfl_xor(mx_, 32));                                     \
    if (__any(mx_ > m_run + 8.0f)) {                                           \
      const float mnew_ = fmaxf(m_run, mx_);                                   \
      const float alpha_ = __expf(m_run - mnew_);                              \
      m_run = mnew_;                                                           \
      l_run *= alpha_;                                                         \
      _Pragma("unroll")                                                        \
      for (int dg = 0; dg < 2; ++dg)                                           \
        _Pragma("unroll")                                                      \
        for (int i = 0; i < 16; ++i) o[dg][i] *= alpha_;                       \
    }                                                                          \
    float ps_ = 0.f;                                                           \
    _Pragma("unroll")                                                          \
    for (int g = 0; g < 2; ++g)                                                \
      _Pragma("unroll")                                                        \
      for (int r = 0; r < 16; ++r) {                                           \
        const float p_ = __expf((SCCUR)[g][r] - m_run);                        \
        (SCCUR)[g][r] = p_;                                                    \
        ps_ += p_;                                                             \
      }                                                                        \
    ps_ += __shfl_xor(ps_, 32);                                                \
    l_run += ps_;                                                              \
    short8 pf_[4];                                                             \
    _Pragma("unroll")                                                          \
    for (int ks = 0; ks < 4; ++ks)                                             \
      _Pragma("unroll")                                                        \
      for (int j = 0; j < 8; ++j)                                              \
        pf_[ks][j] = (short)f2bf((SCCUR)[ks >> 1][8 * (ks & 1) + j]);          \
    _Pragma("unroll")                                                          \
    for (int dg = 0; dg < 2; ++dg) {                                           \
      const int d_ = dg * 32 + l31;                                            \
      const int hv_ = (d_ ^ (d_ >> 3)) & 7;                                    \
      const ushort* vp_ = &Vt[grp][t_ & 1][d_ * 64];                           \
      _Pragma("unroll")                                                        \
      for (int ks = 0; ks < 4; ++ks) {                                         \
        short8 vf_ = *(const short8*)&vp_[(((ks * 2 + lhalf) ^ hv_) & 7) * 8]; \
        o[dg] = __builtin_amdgcn_mfma_f32_32x32x16_bf16(vf_, pf_[ks], o[dg], 0, 0, 0); \
      }                                                                        \
    }                                                                          \
    __builtin_amdgcn_s_setprio(0);                                             \
    if (pre1_) VSCATTER_(Vt[grp][(t_ + 1) & 1]);                               \
    __syncthreads();                                                           \
  }

  // ---- prologue: each group stages its tiles 0,1 -> LDS, V(0); QK(0) -> scA ----
  {
    const ushort* k0 = qkv + base + gkoff + (size_t)srow * 3072 + 64;
    gld_lds16(&Ks[grp][0][ltid * 8],        k0 + scs * 8);
    gld_lds16(&Ks[grp][0][2048 + ltid * 8], k0 + (size_t)32 * 3072 + (scs ^ 4) * 8);
    const ushort* k1 = k0 + (size_t)64 * 3072;
    gld_lds16(&Ks[grp][1][ltid * 8],        k1 + scs * 8);
    gld_lds16(&Ks[grp][1][2048 + ltid * 8], k1 + (size_t)32 * 3072 + (scs ^ 4) * 8);
    #pragma unroll
    for (int kk = 0; kk < 4; ++kk)
      vr[kk] = *(const us4*)(qkv + base + gkoff + (size_t)(kg * 4 + kk) * 3072 + 128 + d0);
    VSCATTER_(Vt[grp][0]);
    __syncthreads();
    QKT_(scA, Ks[grp][0]);
  }

  for (int tp = 0; tp < NT; tp += 2) {
    HALF_(tp,     scA, scB);
    HALF_(tp + 1, scB, scA);
  }

  // ---- combine the two groups' partials (LDS handoff, XOR-swizzled rows) ----
  float* cb   = (float*)&Vt[0][0][0];      // 128 x 64 f32 = 32 KB
  float2* cml = (float2*)&Ks[0][0][0];     // 128 x 8 B = 1 KB
  const int qloc = (wid & 3) * 32 + l31;
  const int cswz = (qloc & 7) << 3;
  if (grp == 1) {
    #pragma unroll
    for (int dg = 0; dg < 2; ++dg)
      #pragma unroll
      for (int quad = 0; quad < 4; ++quad) {
        f32x4 w;
        #pragma unroll
        for (int r = 0; r < 4; ++r) w[r] = o[dg][quad * 4 + r];
        *(f32x4*)&cb[qloc * 64 + ((dg * 32 + quad * 8 + lhalf * 4) ^ cswz)] = w;
      }
    if (lhalf == 0) cml[qloc] = make_float2(m_run, l_run);
  }
  __syncthreads();
  if (grp == 0) {
    const float2 ml1 = cml[qloc];
    const float m = fmaxf(m_run, ml1.x);
    const float w0 = __expf(m_run - m), w1 = __expf(ml1.x - m);
    const float inv = 1.0f / (l_run * w0 + ml1.y * w1);
    ushort* vout = values + ((size_t)bh * S_ + q) * 64;
    #pragma unroll
    for (int dg = 0; dg < 2; ++dg)
      #pragma unroll
      for (int quad = 0; quad < 4; ++quad) {
        const f32x4 o1 = *(const f32x4*)&cb[qloc * 64 + ((dg * 32 + quad * 8 + lhalf * 4) ^ cswz)];
        us4 w;
        #pragma unroll
        for (int r = 0; r < 4; ++r)
          w[r] = f2bf((o[dg][quad * 4 + r] * w0 + o1[r] * w1) * inv);
        *(us4*)(vout + dg * 32 + quad * 8 + lhalf * 4) = w;
      }
  }
#undef HALF_
#undef VSCATTER_
#undef QKT_
}

// ---------------- launch ----------------

extern "C" void kernel_launch(void* const* d_in, const int* in_sizes, int n_in,
                              void* d_out, int out_size, void* d_ws, size_t ws_size,
                              hipStream_t stream) {
  const float* x    = (const float*)d_in[0];
  const float* mask = (const float*)d_in[1];
  const float* Wqkv = (const float*)d_in[2];
  const float* bqkv = (const float*)d_in[3];
  const float* Wo   = (const float*)d_in[4];
  const float* bo   = (const float*)d_in[5];
  float* out = (float*)d_out;

  char* ws = (char*)d_ws;
  ushort* xbf    = (ushort*)(ws + 0);
  ushort* vals   = (ushort*)(ws + 0);
  ushort* wqkvT  = (ushort*)(ws + 8388608);
  ushort* woT    = (ushort*)(ws + 14680064);
  ushort* qkv    = (ushort*)(ws + 16777216);

  prep_all<<<8192, 256, 0, stream>>>((const float4*)x, xbf, Wqkv, wqkvT, Wo, woT);
  gemm_bt<true><<<dim3((B_ * S_) / 128, (3 * D_) / 128), 256, 0, stream>>>(
      xbf, wqkvT, bqkv, qkv, nullptr, B_ * S_, 3 * D_, D_);
  flash_attn<<<dim3(S_ / 128, B_ * H_), 512, 0, stream>>>(qkv, mask, vals);
  gemm_bt<false><<<dim3((B_ * S_) / 128, D_ / 128), 256, 0, stream>>>(
      vals, woT, bo, nullptr, out, B_ * S_, D_, D_);
}